// Round 3
// baseline (417.159 us; speedup 1.0000x reference)
//
#include <hip/hip_runtime.h>
#include <math.h>

// ---------------------------------------------------------------------------
// Fully fused: each block rebuilds the 16x16 circuit unitary in-block
// (shfl-parallel state evolution, threads 0..255 = 16 columns x 16 amps),
// stores it to LDS, then runs the bulk batched forward. NO d_ws usage, NO
// inter-kernel dependency — round-2's post-timing divergence implicated the
// scratch-based two-kernel structure (first call passed, later calls were
// deterministically wrong), so the entire class is removed.
// ---------------------------------------------------------------------------

struct cpx { float r, i; };

__device__ inline cpx cmul(cpx a, cpx b) { return {a.r*b.r - a.i*b.i, a.r*b.i + a.i*b.r}; }
__device__ inline cpx cadd(cpx a, cpx b) { return {a.r + b.r, a.i + b.i}; }

// Generic 2x2 gate on wire with bit BIT. Thread holds amplitude j of its
// column; partner amplitude j^BIT lives in lane tid^BIT of the same wave.
template<int BIT>
__device__ inline void apply2(cpx& x, int j, cpx g00, cpx g01, cpx g10, cpx g11) {
  cpx p;
  p.r = __shfl_xor(x.r, BIT, 64);
  p.i = __shfl_xor(x.i, BIT, 64);
  const bool hi = (j & BIT) != 0;
  const cpx ca = hi ? g11 : g00;   // coefficient on own amplitude
  const cpx cb = hi ? g10 : g01;   // coefficient on partner amplitude
  x = cadd(cmul(ca, x), cmul(cb, p));
}

// CNOT control-bit CB, target-bit TB: new[j] = (j&CB) ? old[j^TB] : old[j]
template<int CB, int TB>
__device__ inline void cnotg(cpx& x, int j) {
  cpx p;
  p.r = __shfl_xor(x.r, TB, 64);
  p.i = __shfl_xor(x.i, TB, 64);
  if (j & CB) x = p;               // per-lane cndmask
}

// PennyLane U3(theta, phi, lam): [[ct, -e^{il} st], [e^{ip} st, e^{i(p+l)} ct]]
template<int BIT>
__device__ inline void u3g(cpx& x, int j, float th, float ph, float lm) {
  float st, ct; __sincosf(0.5f * th, &st, &ct);
  float sp, cp; __sincosf(ph, &sp, &cp);
  float sl, cl; __sincosf(lm, &sl, &cl);
  const cpx g00 = { ct, 0.f };
  const cpx g01 = { -cl * st, -sl * st };
  const cpx g10 = {  cp * st,  sp * st };
  const cpx g11 = { (cp*cl - sp*sl) * ct, (sp*cl + cp*sl) * ct };
  apply2<BIT>(x, j, g00, g01, g10, g11);
}

// RY: lo row: c*x - s*p ; hi row: s*p + c*x
template<int BIT>
__device__ inline void ryg(cpx& x, int j, float t) {
  float s, c; __sincosf(0.5f * t, &s, &c);
  const float pr = __shfl_xor(x.r, BIT, 64);
  const float pi = __shfl_xor(x.i, BIT, 64);
  const float ss = (j & BIT) ? s : -s;
  x.r = fmaf(ss, pr, c * x.r);
  x.i = fmaf(ss, pi, c * x.i);
}

// RZ: lo: x *= (c - i s) ; hi: x *= (c + i s)
template<int BIT>
__device__ inline void rzg(cpx& x, int j, float t) {
  float s, c; __sincosf(0.5f * t, &s, &c);
  const float ss = (j & BIT) ? s : -s;
  const float nr = fmaf(-ss, x.i, c * x.r);
  const float ni = fmaf( ss, x.r, c * x.i);
  x.r = nr; x.i = ni;
}

// SU4 block on wires (A,B): U3,U3,CNOT(A,B),RY(A),RZ(B),CNOT(B,A),RY(A),CNOT(A,B),U3,U3
template<int A, int B>
__device__ inline void su4g(cpx& x, int j, const float* const* W) {
  constexpr int BA = 8 >> A, BB = 8 >> B;
  u3g<BA>(x, j, W[0][0], W[0][1], W[0][2]);
  u3g<BB>(x, j, W[1][0], W[1][1], W[1][2]);
  cnotg<BA, BB>(x, j);
  ryg<BA>(x, j, W[2][0]);
  rzg<BB>(x, j, W[3][0]);
  cnotg<BB, BA>(x, j);
  ryg<BA>(x, j, W[4][0]);
  cnotg<BA, BB>(x, j);
  u3g<BA>(x, j, W[5][0], W[5][1], W[5][2]);
  u3g<BB>(x, j, W[6][0], W[6][1], W[6][2]);
}

#define BLK 512
#define G   8

__global__ __launch_bounds__(BLK, 2)
void quanv_fused(const float4* __restrict__ pat,
                 const float* w0,  const float* w1,  const float* w2,
                 const float* w3,  const float* w4,  const float* w5,
                 const float* w6,  const float* w7,  const float* w8,
                 const float* w9,  const float* w10, const float* w11,
                 const float* w12, const float* w13,
                 float4* __restrict__ out, int B) {
  __shared__ float2 Ush[256];   // Ush[k*16 + j] = U[k][j]

  const int tid  = threadIdx.x;
  const int base = blockIdx.x * (BLK * G) + tid;

  // ---- issue patch loads early (HBM latency overlaps the build) ----
  float4 p[G];
#pragma unroll
  for (int g = 0; g < G; ++g) {
    const int e = base + g * BLK;
    p[g] = (e < B) ? pat[e] : make_float4(0.f, 0.f, 0.f, 0.f);
  }

  // ---- in-block unitary build: threads 0..255, waves 0..3 ----
  if (tid < 256) {
    const int col = tid >> 4;
    const int j   = tid & 15;
    cpx x = { (j == col) ? 1.f : 0.f, 0.f };
    {
      const float* WA[7] = { w0, w1, w2, w3, w4, w5, w6 };
      su4g<0,1>(x, j, WA); su4g<1,2>(x, j, WA);
      su4g<2,3>(x, j, WA); su4g<3,0>(x, j, WA);
    }
    {
      const float* WB[7] = { w7, w8, w9, w10, w11, w12, w13 };
      su4g<0,1>(x, j, WB); su4g<1,2>(x, j, WB);
      su4g<2,3>(x, j, WB); su4g<3,0>(x, j, WB);
    }
    Ush[j * 16 + col] = make_float2(x.r, x.i);   // row j, column col
  }

  // ---- psi0 = product state from sigmoid-scaled RY angles ----
  const float HPI = 1.5707963267948966f;  // pi/2
  float psi[G][16];
  float4 acc[G];
#pragma unroll
  for (int g = 0; g < G; ++g) {
    const float h0 = HPI / (1.f + __expf(-p[g].x));
    const float h1 = HPI / (1.f + __expf(-p[g].y));
    const float h2 = HPI / (1.f + __expf(-p[g].z));
    const float h3 = HPI / (1.f + __expf(-p[g].w));
    float c0, s0, c1, s1, c2, s2, c3, s3;
    __sincosf(h0, &s0, &c0); __sincosf(h1, &s1, &c1);
    __sincosf(h2, &s2, &c2); __sincosf(h3, &s3, &c3);
    const float q01[4] = { c0*c1, c0*s1, s0*c1, s0*s1 };
    const float q23[4] = { c2*c3, c2*s3, s2*c3, s2*s3 };
#pragma unroll
    for (int j = 0; j < 16; ++j) psi[g][j] = q01[j >> 2] * q23[j & 3];
    acc[g] = make_float4(0.f, 0.f, 0.f, 0.f);
  }

  __syncthreads();

  // ---- bulk: |U psi0|^2 -> signed sums (verified math from round 2) ----
#pragma unroll
  for (int k = 0; k < 16; ++k) {
    float2 row[16];
#pragma unroll
    for (int j = 0; j < 16; ++j) row[j] = Ush[k * 16 + j];   // uniform broadcast
#pragma unroll
    for (int g = 0; g < G; ++g) {
      float re = 0.f, im = 0.f;
#pragma unroll
      for (int j = 0; j < 16; ++j) {
        re = fmaf(row[j].x, psi[g][j], re);
        im = fmaf(row[j].y, psi[g][j], im);
      }
      const float pr = fmaf(re, re, im * im);
      acc[g].x += (k & 8) ? -pr : pr;
      acc[g].y += (k & 4) ? -pr : pr;
      acc[g].z += (k & 2) ? -pr : pr;
      acc[g].w += (k & 1) ? -pr : pr;
    }
  }

#pragma unroll
  for (int g = 0; g < G; ++g) {
    const int e = base + g * BLK;
    if (e < B) out[e] = acc[g];
  }
}

// ---------------------------------------------------------------------------
extern "C" void kernel_launch(void* const* d_in, const int* in_sizes, int n_in,
                              void* d_out, int out_size, void* d_ws, size_t ws_size,
                              hipStream_t stream) {
  (void)d_ws; (void)ws_size;   // deliberately unused — see header comment
  const int B = in_sizes[0] / 4;
  const int blocks = (B + BLK * G - 1) / (BLK * G);
  quanv_fused<<<blocks, BLK, 0, stream>>>(
      (const float4*)d_in[0],
      (const float*)d_in[1],  (const float*)d_in[2],  (const float*)d_in[3],
      (const float*)d_in[4],  (const float*)d_in[5],  (const float*)d_in[6],
      (const float*)d_in[7],  (const float*)d_in[8],  (const float*)d_in[9],
      (const float*)d_in[10], (const float*)d_in[11], (const float*)d_in[12],
      (const float*)d_in[13], (const float*)d_in[14],
      (float4*)d_out, B);
}